// Round 5
// baseline (87.502 us; speedup 1.0000x reference)
//
#include <hip/hip_runtime.h>

// Phase vocoder (fixed rate 1.2) + abs() of complex result == magnitude interp:
//   out[row,t] = a * n[idx+1] + (1-a) * n[idx],  n[k] = |spec[row,k]|, n[2048]=0
//   tf = (float)t * 1.2f, idx = floor(tf), a = tf - idx.
//
// Key: RATE = 12/10 exactly -> 10 consecutive outputs consume exactly 12
// consecutive inputs (zero overlap between threads). floor(1.2*s), s=0..9,
// is the compile-time table {0,1,2,3,4,6,7,8,9,10} (f32 rounding can't cross
// an integer boundary: fractional parts are >=0.2 vs <=2.2e-4 error; exact-
// integer cases have 1.2f > 1.2 so the product rounds to >= the integer).
// So: no LDS, no barrier, static register indexing, exactly-once reads.

#define T_IN   2048
#define T_OUT  1707
#define UPT    10            // outputs per thread
#define IPT    12            // inputs per thread (= UPT * 1.2 exactly)
#define UPR    171           // units per row = ceil(T_OUT / UPT); last does 7

typedef float vf2 __attribute__((ext_vector_type(2), aligned(4)));

__global__ __launch_bounds__(256) void pv_stream_kernel(
    const float* __restrict__ re, const float* __restrict__ im,
    float* __restrict__ out, unsigned total_units) {
    unsigned unit = blockIdx.x * 256u + threadIdx.x;
    if (unit >= total_units) return;
    unsigned row = unit / UPR;               // compiler magic-mul
    int vr = (int)(unit - row * UPR);        // 0..170 within the row

    const float* __restrict__ rr = re + (size_t)row * T_IN + (size_t)(IPT * vr);
    const float* __restrict__ ir = im + (size_t)row * T_IN + (size_t)(IPT * vr);

    float r[IPT], q[IPT];
    if (vr < UPR - 1) {
        // 48B-aligned window: 3 float4 loads per tensor
        float4 a0 = ((const float4*)rr)[0];
        float4 a1 = ((const float4*)rr)[1];
        float4 a2 = ((const float4*)rr)[2];
        float4 b0 = ((const float4*)ir)[0];
        float4 b1 = ((const float4*)ir)[1];
        float4 b2 = ((const float4*)ir)[2];
        r[0]=a0.x; r[1]=a0.y; r[2]=a0.z;  r[3]=a0.w;
        r[4]=a1.x; r[5]=a1.y; r[6]=a1.z;  r[7]=a1.w;
        r[8]=a2.x; r[9]=a2.y; r[10]=a2.z; r[11]=a2.w;
        q[0]=b0.x; q[1]=b0.y; q[2]=b0.z;  q[3]=b0.w;
        q[4]=b1.x; q[5]=b1.y; q[6]=b1.z;  q[7]=b1.w;
        q[8]=b2.x; q[9]=b2.y; q[10]=b2.z; q[11]=b2.w;
    } else {
        // tail unit: base = 2040, only 8 in-row floats; indices >= 2048 are
        // the zero pad (and would be OOB on the final row) -> zeros.
        float4 a0 = ((const float4*)rr)[0];
        float4 a1 = ((const float4*)rr)[1];
        float4 b0 = ((const float4*)ir)[0];
        float4 b1 = ((const float4*)ir)[1];
        r[0]=a0.x; r[1]=a0.y; r[2]=a0.z; r[3]=a0.w;
        r[4]=a1.x; r[5]=a1.y; r[6]=a1.z; r[7]=a1.w;
        r[8]=0.0f; r[9]=0.0f; r[10]=0.0f; r[11]=0.0f;
        q[0]=b0.x; q[1]=b0.y; q[2]=b0.z; q[3]=b0.w;
        q[4]=b1.x; q[5]=b1.y; q[6]=b1.z; q[7]=b1.w;
        q[8]=0.0f; q[9]=0.0f; q[10]=0.0f; q[11]=0.0f;
    }

    float n[IPT];
#pragma unroll
    for (int k = 0; k < IPT; ++k) n[k] = sqrtf(r[k] * r[k] + q[k] * q[k]);

    // static floor(1.2*s) table -> all n[] indices compile-time constants
    const int L[UPT] = {0, 1, 2, 3, 4, 6, 7, 8, 9, 10};
    const float tb = (float)(IPT * vr);      // exact integer (< 2^24)
    float o[UPT];
#pragma unroll
    for (int s = 0; s < UPT; ++s) {
        float tf = (float)(UPT * vr + s) * 1.2f;   // matches ref time_steps
        float a  = tf - (tb + (float)L[s]);        // == tf - floor(tf), exact
        o[s] = a * n[L[s] + 1] + (1.0f - a) * n[L[s]];
    }

    float* __restrict__ orow = out + (size_t)row * T_OUT + (size_t)(UPT * vr);
    if (vr < UPR - 1) {
#pragma unroll
        for (int s2 = 0; s2 < 5; ++s2) {
            vf2 v; v.x = o[2 * s2]; v.y = o[2 * s2 + 1];
            __builtin_nontemporal_store(v, (vf2*)(orow + 2 * s2));
        }
    } else {
        // tail: 7 valid outputs (t = 1700..1706)
#pragma unroll
        for (int s2 = 0; s2 < 3; ++s2) {
            vf2 v; v.x = o[2 * s2]; v.y = o[2 * s2 + 1];
            __builtin_nontemporal_store(v, (vf2*)(orow + 2 * s2));
        }
        __builtin_nontemporal_store(o[6], orow + 6);
    }
}

extern "C" void kernel_launch(void* const* d_in, const int* in_sizes, int n_in,
                              void* d_out, int out_size, void* d_ws, size_t ws_size,
                              hipStream_t stream) {
    const float* re = (const float*)d_in[0];
    const float* im = (const float*)d_in[1];
    float* out = (float*)d_out;

    const int nrows = in_sizes[0] / T_IN;            // 16 * 1025 = 16400
    unsigned total_units = (unsigned)nrows * UPR;    // 2,804,400
    unsigned grid = (total_units + 255u) / 256u;

    pv_stream_kernel<<<grid, 256, 0, stream>>>(re, im, out, total_units);
}

// Round 6
// 61.964 us; speedup vs baseline: 1.4121x; 1.4121x over previous
//
#include <hip/hip_runtime.h>

// Phase vocoder (fixed rate 1.2) + abs() of complex result == magnitude interp:
//   out[row,t] = a * n[idx+1] + (1-a) * n[idx],  n[k] = |spec[row,k]|, n[2048]=0
//   tf = (float)t * 1.2f, idx = floor(tf), a = tf - idx.
//
// RATE = 12/10 exactly: 10 consecutive outputs consume exactly 12 consecutive
// inputs, zero overlap between threads; floor(1.2*s), s=0..9 is the static
// table {0,1,2,3,4,6,7,8,9,10} (f32 rounding cannot cross a boundary).
// R5 lesson: per-thread 40B nt stores caused 2x HBM write amplification
// (WRITE_SIZE 112->220 MB). Fix: wave-private LDS transpose, then coalesced
// lane-major float4 nt stores. No __syncthreads anywhere (LDS deps are
// wave-internal; ds ops are in-order per wave).

#define T_IN   2048
#define T_OUT  1707
#define UPT    10            // outputs per unit(thread)
#define IPT    12            // inputs per unit
#define UPR    171           // units per row; unit 170 emits only 7 outputs

typedef float vf4 __attribute__((ext_vector_type(4)));
typedef float vf2 __attribute__((ext_vector_type(2)));

__global__ __launch_bounds__(192) void pv_wave_kernel(
    const float* __restrict__ re, const float* __restrict__ im,
    float* __restrict__ out) {
    // wave-private transpose scratch: 3 waves x 640 floats = 7.5 KB
    __shared__ __align__(16) float lds[3][640];

    const int row  = blockIdx.x;
    const int tid  = threadIdx.x;
    const int wv   = tid >> 6;          // wave 0..2 within the row
    const int lane = tid & 63;
    const int vr   = (wv << 6) + lane;  // unit index within row, 0..191

    if (vr < UPR) {
        const float* __restrict__ rr = re + (size_t)row * T_IN + IPT * vr;
        const float* __restrict__ ir = im + (size_t)row * T_IN + IPT * vr;

        float r[IPT], q[IPT];
        if (vr < UPR - 1) {
            // 48B window, 16B-aligned: 3 float4 loads per tensor
            float4 a0 = ((const float4*)rr)[0];
            float4 a1 = ((const float4*)rr)[1];
            float4 a2 = ((const float4*)rr)[2];
            float4 b0 = ((const float4*)ir)[0];
            float4 b1 = ((const float4*)ir)[1];
            float4 b2 = ((const float4*)ir)[2];
            r[0]=a0.x; r[1]=a0.y; r[2]=a0.z;  r[3]=a0.w;
            r[4]=a1.x; r[5]=a1.y; r[6]=a1.z;  r[7]=a1.w;
            r[8]=a2.x; r[9]=a2.y; r[10]=a2.z; r[11]=a2.w;
            q[0]=b0.x; q[1]=b0.y; q[2]=b0.z;  q[3]=b0.w;
            q[4]=b1.x; q[5]=b1.y; q[6]=b1.z;  q[7]=b1.w;
            q[8]=b2.x; q[9]=b2.y; q[10]=b2.z; q[11]=b2.w;
        } else {
            // tail unit: base 2040, 8 in-row floats; >=2048 is the zero pad
            float4 a0 = ((const float4*)rr)[0];
            float4 a1 = ((const float4*)rr)[1];
            float4 b0 = ((const float4*)ir)[0];
            float4 b1 = ((const float4*)ir)[1];
            r[0]=a0.x; r[1]=a0.y; r[2]=a0.z; r[3]=a0.w;
            r[4]=a1.x; r[5]=a1.y; r[6]=a1.z; r[7]=a1.w;
            r[8]=0.0f; r[9]=0.0f; r[10]=0.0f; r[11]=0.0f;
            q[0]=b0.x; q[1]=b0.y; q[2]=b0.z; q[3]=b0.w;
            q[4]=b1.x; q[5]=b1.y; q[6]=b1.z; q[7]=b1.w;
            q[8]=0.0f; q[9]=0.0f; q[10]=0.0f; q[11]=0.0f;
        }

        float n[IPT];
#pragma unroll
        for (int k = 0; k < IPT; ++k) n[k] = sqrtf(r[k] * r[k] + q[k] * q[k]);

        const int L[UPT] = {0, 1, 2, 3, 4, 6, 7, 8, 9, 10};
        const float tb = (float)(IPT * vr);   // exact integer
        float o[UPT];
#pragma unroll
        for (int s = 0; s < UPT; ++s) {
            float tf = (float)(UPT * vr + s) * 1.2f;  // matches ref time_steps
            float a  = tf - (tb + (float)L[s]);       // == tf - floor(tf)
            o[s] = a * n[L[s] + 1] + (1.0f - a) * n[L[s]];
        }

        // park in this wave's LDS slice (bank stride 10 -> 2-way alias, free)
        float* slice = lds[wv];
#pragma unroll
        for (int s2 = 0; s2 < 5; ++s2) {
            vf2 v; v.x = o[2 * s2]; v.y = o[2 * s2 + 1];
            *(vf2*)&slice[UPT * lane + 2 * s2] = v;
        }
    }

    // lane-major coalesced nt stores of this wave's contiguous output span.
    // wave 0/1: 640 floats; wave 2: 427 floats (units 128..170, tail has 7).
    const int u0  = wv << 6;
    const int cnt = (u0 + 64 < UPR) ? 640 : (T_OUT - UPT * u0);
    float* __restrict__ gbase = out + (size_t)row * T_OUT + (size_t)(UPT * u0);
    const float* slice = lds[wv];
#pragma unroll
    for (int p = 0; p < 3; ++p) {
        int off = (p << 8) + (lane << 2);     // 4*(64p + lane)
        if (off + 4 <= cnt) {
            vf4 v = *(const vf4*)&slice[off];
            __builtin_nontemporal_store(v, (vf4*)(gbase + off));
        } else if (off < cnt) {
            for (int t = off; t < cnt; ++t)
                __builtin_nontemporal_store(slice[t], gbase + t);
        }
    }
}

extern "C" void kernel_launch(void* const* d_in, const int* in_sizes, int n_in,
                              void* d_out, int out_size, void* d_ws, size_t ws_size,
                              hipStream_t stream) {
    const float* re = (const float*)d_in[0];
    const float* im = (const float*)d_in[1];
    float* out = (float*)d_out;

    const int nrows = in_sizes[0] / T_IN;    // 16 * 1025 = 16400
    pv_wave_kernel<<<nrows, 192, 0, stream>>>(re, im, out);
}